// Round 6
// baseline (318.086 us; speedup 1.0000x reference)
//
#include <hip/hip_runtime.h>
#include <hip/hip_bf16.h>

#define N_NEURON 1024
#define N_PEPTIDE 16
#define N_GENES 1
#define BATCH 2048
#define SQ 32
#define DT_STEP (1.0f/120.0f)
#define S_STRIDE (N_NEURON + N_GENES + N_NEURON + N_NEURON*N_PEPTIDE) // 18433

typedef __attribute__((ext_vector_type(8))) short short8;
typedef __attribute__((ext_vector_type(4))) short short4v;
typedef __attribute__((ext_vector_type(4))) float floatx4;
typedef __attribute__((ext_vector_type(2))) float floatx2;
// S_STRIDE is odd, so state-relative offsets are only dword-aligned.
typedef floatx4 floatx4u __attribute__((aligned(4)));
typedef floatx2 floatx2u __attribute__((aligned(4)));

// -------------------------------------------------------------------------
// Kernel 1: synapse (K x N fp32, row-major) -> synT (N x K bf16, row-major)
// -------------------------------------------------------------------------
__global__ __launch_bounds__(256) void synT_cast(const float* __restrict__ syn,
                                                 __hip_bfloat16* __restrict__ synT) {
    __shared__ float tile[32][33];
    const int n0 = blockIdx.x * 32;
    const int k0 = blockIdx.y * 32;
    const int tx = threadIdx.x & 31;
    const int ty = threadIdx.x >> 5; // 0..7
    #pragma unroll
    for (int i = 0; i < 4; ++i)
        tile[ty + i*8][tx] = syn[(long)(k0 + ty + i*8) * N_NEURON + n0 + tx];
    __syncthreads();
    #pragma unroll
    for (int i = 0; i < 4; ++i)
        synT[(long)(n0 + ty + i*8) * N_NEURON + k0 + tx] =
            __float2bfloat16(tile[tx][ty + i*8]);
}

// -------------------------------------------------------------------------
// Kernel 2a: streaming firing. One block per batch row, 4 neurons/thread.
// -------------------------------------------------------------------------
__global__ __launch_bounds__(256) void firing_k(
    const float* __restrict__ state,
    const float* __restrict__ noise,
    float* __restrict__ firing_out,
    float* __restrict__ state_new,
    __hip_bfloat16* __restrict__ fbf)
{
    const int b = blockIdx.x;
    const int tid = threadIdx.x;
    const long bS = (long)b * S_STRIDE;
    const int n4 = tid * 4;

    floatx4 ab = *(const floatx4u*)(state + bS + n4);
    floatx4 nr = *(const floatx4u*)(state + bS + N_NEURON + N_GENES + n4);
    floatx4 nz = *(const floatx4*)(noise + (long)b * N_NEURON + n4);
    floatx4 f;
    short4v hb;
    #pragma unroll
    for (int j = 0; j < 4; ++j) {
        float fr = fmaxf(nr[j], 0.f) * ab[j];
        fr = -(fr + 0.01f) * log1pf(-nz[j]);
        fr = fminf(fmaxf(fr, 0.f), 10.f);
        f[j] = fr;
        __hip_bfloat16 h = __float2bfloat16(fr);
        hb[j] = *reinterpret_cast<short*>(&h);
    }
    *(floatx4*)(firing_out + (long)b * N_NEURON + n4) = f;      // re-read
    *(short4v*)(fbf + (long)b * N_NEURON + n4) = hb;            // re-read
    __builtin_nontemporal_store(ab, (floatx4u*)(state_new + bS + n4));
    if (tid == 0) state_new[bS + N_NEURON] = state[bS + N_NEURON];
}

// -------------------------------------------------------------------------
// Kernel 2b: pep_stream — copy-shaped streaming stencil.
// 32768 blocks x 256 threads (16 blocks per batch row, 64 neurons each),
// NO LDS, NO barriers. Thread owns one 16B p-quad of one neuron.
// -------------------------------------------------------------------------
__global__ __launch_bounds__(256) void pep_stream(
    const float* __restrict__ u,
    const float* __restrict__ state,
    const float* __restrict__ D,
    const float* __restrict__ prod_g,
    const float* __restrict__ decay_g,
    const float* __restrict__ pact_g,
    const float* __restrict__ ndecay_g,
    const float* __restrict__ inL,
    const float* __restrict__ firing,   // f32 firing from firing_k
    float* __restrict__ state_new)
{
    const int g   = blockIdx.x;          // 0..32767
    const int b   = g >> 4;              // batch row
    const int n0  = (g & 15) * 64;       // 64 neurons per block -> full 1024
    const int tid = threadIdx.x;
    const int pq  = tid & 3;
    const int nl  = tid >> 2;            // 0..63
    const int p0q = pq * 4;
    const int n   = n0 + nl;
    const int si  = n >> 5, sj = n & 31;
    const long bS = (long)b * S_STRIDE;

    const float* __restrict__ pep = state + bS + 2 * N_NEURON + N_GENES;
    float* __restrict__ pep_new = state_new + bS + 2 * N_NEURON + N_GENES;

    // issue all global reads up front
    const int idx = (n << 4) + p0q;
    const floatx4 c  = *(const floatx4u*)(pep + idx);
    const floatx4 vu = *(const floatx4u*)(pep + ((((si + 31) & 31) * 32 + sj) << 4) + p0q);
    const floatx4 vd = *(const floatx4u*)(pep + ((((si +  1) & 31) * 32 + sj) << 4) + p0q);
    const floatx4 vl = *(const floatx4u*)(pep + ((si * 32 + ((sj + 31) & 31)) << 4) + p0q);
    const floatx4 vr = *(const floatx4u*)(pep + ((si * 32 + ((sj +  1) & 31)) << 4) + p0q);
    const float fn = firing[(long)b * N_NEURON + n];

    floatx4 Dq, prq, deq, paq;
    #pragma unroll
    for (int j = 0; j < 4; ++j) {
        Dq[j]  = fabsf(D[p0q + j]);
        prq[j] = fabsf(prod_g[p0q + j]);
        deq[j] = fabsf(decay_g[p0q + j]);
        paq[j] = pact_g[p0q + j];
    }

    floatx4 lap = vu + vd + vl + vr - 4.f * c;
    floatx4 outv = c + DT_STEP * (prq * fn - deq * c + Dq * lap);
    __builtin_nontemporal_store(outv, (floatx4u*)(pep_new + idx));

    // pact-dot over the 16 peptides (4 lanes x 4 each)
    float ps = c[0]*paq[0] + c[1]*paq[1] + c[2]*paq[2] + c[3]*paq[3];
    ps += __shfl_xor(ps, 1);
    ps += __shfl_xor(ps, 2);
    if (pq == 0) {
        const float ab_ = state[bS + n];
        const float nr_ = state[bS + N_NEURON + N_GENES + n];
        const float nm  = nr_ * ab_;
        const float pc2 = state[bS + N_NEURON];
        const float ndecay = fabsf(ndecay_g[0]);
        const float u_b = u[b];
        const float c0 = nm + DT_STEP * (ps * pc2 - nm * ndecay + inL[n] * u_b);
        state_new[bS + N_NEURON + N_GENES + n] = c0;   // re-read by gemm
    }
}

// -------------------------------------------------------------------------
// Kernel 3: bf16 MFMA GEMM (unchanged).
// -------------------------------------------------------------------------
__device__ __forceinline__ void stage8k(const __hip_bfloat16* __restrict__ gbase,
                                        char* lhalf, int row0, int k0,
                                        int w, int lane)
{
    #pragma unroll
    for (int i = 0; i < 2; ++i) {
        const int ch  = w * 2 + i;                // 0..7, 1KB each
        const int o   = ch * 1024 + lane * 16;    // linear byte offset in half
        const int row = o >> 7;                   // 0..63
        const int c16 = (o >> 4) & 7;             // 16B chunk within row
        const int cl  = c16 ^ (row & 7);          // inverse swizzle on source
        const __hip_bfloat16* g = gbase + (long)(row0 + row) * 1024 + k0 + cl * 8;
        __builtin_amdgcn_global_load_lds(
            (const __attribute__((address_space(1))) void*)g,
            (__attribute__((address_space(3))) void*)(lhalf + ch * 1024),
            16, 0, 0);
    }
}

__device__ __forceinline__ short8 lds_frag(const char* lhalf, int row, int c16) {
    const int cl = c16 ^ (row & 7);               // swizzled read
    return *(const short8*)(lhalf + row * 128 + cl * 16);
}

__global__ __launch_bounds__(256) void gemm_epi(
    const __hip_bfloat16* __restrict__ A,   // firing bf16 [2048,1024]
    const __hip_bfloat16* __restrict__ BT,  // synT bf16 [1024,1024]
    const float* __restrict__ state,
    float* __restrict__ state_new)
{
    __shared__ __align__(16) char lds[2][16384]; // [buf][A 8KB | B 8KB]
    const int tid = threadIdx.x;
    const int w = tid >> 6, lane = tid & 63;
    const int q = lane >> 4, l16 = lane & 15;
    const int m0 = blockIdx.x * 64;
    const int n0 = blockIdx.y * 64;
    const int wm = (w & 1) * 32, wn = (w >> 1) * 32;

    // prefetch epilogue operands; latency hides under the K-loop
    float abv[2][2][4], c0v[2][2][4];
    #pragma unroll
    for (int mi = 0; mi < 2; ++mi)
    #pragma unroll
    for (int ni = 0; ni < 2; ++ni)
    #pragma unroll
    for (int r = 0; r < 4; ++r) {
        const int m = m0 + wm + mi * 16 + q * 4 + r;
        const int n = n0 + wn + ni * 16 + l16;
        const long sidx = (long)m * S_STRIDE;
        abv[mi][ni][r] = state[sidx + n];
        c0v[mi][ni][r] = state_new[sidx + N_NEURON + N_GENES + n];
    }

    floatx4 acc[2][2] = {};

    stage8k(A,  lds[0],        m0, 0, w, lane);
    stage8k(BT, lds[0] + 8192, n0, 0, w, lane);
    __syncthreads();

#define GEMM_STEP(CUR, T)                                                     \
    {                                                                         \
        if ((T) < 15) {                                                       \
            stage8k(A,  lds[(CUR) ^ 1],        m0, ((T) + 1) * 64, w, lane);  \
            stage8k(BT, lds[(CUR) ^ 1] + 8192, n0, ((T) + 1) * 64, w, lane);  \
        }                                                                     \
        const char* la = lds[(CUR)];                                          \
        const char* lb = lds[(CUR)] + 8192;                                   \
        _Pragma("unroll")                                                     \
        for (int kk = 0; kk < 2; ++kk) {                                      \
            const int c16 = kk * 4 + q;                                       \
            short8 a0 = lds_frag(la, wm + l16,      c16);                     \
            short8 a1 = lds_frag(la, wm + 16 + l16, c16);                     \
            short8 b0 = lds_frag(lb, wn + l16,      c16);                     \
            short8 b1 = lds_frag(lb, wn + 16 + l16, c16);                     \
            acc[0][0] = __builtin_amdgcn_mfma_f32_16x16x32_bf16(a0, b0, acc[0][0], 0, 0, 0); \
            acc[0][1] = __builtin_amdgcn_mfma_f32_16x16x32_bf16(a0, b1, acc[0][1], 0, 0, 0); \
            acc[1][0] = __builtin_amdgcn_mfma_f32_16x16x32_bf16(a1, b0, acc[1][0], 0, 0, 0); \
            acc[1][1] = __builtin_amdgcn_mfma_f32_16x16x32_bf16(a1, b1, acc[1][1], 0, 0, 0); \
        }                                                                     \
        if ((T) < 15) __syncthreads();                                        \
    }

    #pragma unroll
    for (int tt = 0; tt < 8; ++tt) {
        GEMM_STEP(0, tt * 2)
        GEMM_STEP(1, tt * 2 + 1)
    }
#undef GEMM_STEP

    #pragma unroll
    for (int mi = 0; mi < 2; ++mi)
    #pragma unroll
    for (int ni = 0; ni < 2; ++ni)
    #pragma unroll
    for (int r = 0; r < 4; ++r) {
        const int m = m0 + wm + mi * 16 + q * 4 + r;
        const int n = n0 + wn + ni * 16 + l16;
        const long sidx = (long)m * S_STRIDE;
        state_new[sidx + N_NEURON + N_GENES + n] =
            (c0v[mi][ni][r] + DT_STEP * acc[mi][ni][r]) * abv[mi][ni][r];
    }
}

extern "C" void kernel_launch(void* const* d_in, const int* in_sizes, int n_in,
                              void* d_out, int out_size, void* d_ws, size_t ws_size,
                              hipStream_t stream) {
    const float* u      = (const float*)d_in[0];
    const float* state  = (const float*)d_in[1];
    const float* noise  = (const float*)d_in[2];
    const float* D      = (const float*)d_in[3];
    const float* prod   = (const float*)d_in[4];
    const float* decay  = (const float*)d_in[5];
    const float* pact   = (const float*)d_in[6];
    const float* syn    = (const float*)d_in[7];
    const float* ndec   = (const float*)d_in[8];
    const float* inL    = (const float*)d_in[9];

    float* firing = (float*)d_out;                          // [B,N]
    float* state_new = firing + (long)BATCH * N_NEURON;     // [B,S]

    __hip_bfloat16* fbf  = (__hip_bfloat16*)d_ws;           // 4 MB
    __hip_bfloat16* synT = fbf + (long)BATCH * N_NEURON;    // 2 MB

    hipLaunchKernelGGL(synT_cast, dim3(32, 32), dim3(256), 0, stream, syn, synT);
    hipLaunchKernelGGL(firing_k, dim3(BATCH), dim3(256), 0, stream,
                       state, noise, firing, state_new, fbf);
    hipLaunchKernelGGL(pep_stream, dim3(BATCH * 16), dim3(256), 0, stream,
                       u, state, D, prod, decay, pact, ndec, inL,
                       firing, state_new);
    hipLaunchKernelGGL(gemm_epi, dim3(32, 16), dim3(256), 0, stream,
                       fbf, synT, state, state_new);
}